// Round 2
// baseline (2436.914 us; speedup 1.0000x reference)
//
#include <hip/hip_runtime.h>

#define NN 100000      // nodes
#define NE 1000000     // edges
#define NG 1024        // graphs
#define NSG 128        // subgraphs
#define EF 32          // edge feature dim
#define HH 64          // hidden
#define NOUT 32        // output classes
#define NL 3           // layers

// wave-uniform broadcast of lane l's value (v_readlane -> SGPR)
__device__ __forceinline__ float bcastf(float v, int l) {
    return __int_as_float(__builtin_amdgcn_readlane(__float_as_int(v), l));
}

// ---------------------------------------------------------------------------
// per-graph node counts
__global__ void cnt_kernel(const int* __restrict__ batch, float* __restrict__ cnt) {
    int i = blockIdx.x * blockDim.x + threadIdx.x;
    if (i < NN) atomicAdd(&cnt[batch[i]], 1.0f);
}

// per-subgraph weight norms
__global__ void norm_kernel(const int* __restrict__ sgb, const float* __restrict__ w,
                            float* __restrict__ norm) {
    int i = blockIdx.x * blockDim.x + threadIdx.x;
    if (i < NG) atomicAdd(&norm[sgb[i]], w[i]);
}

// ---------------------------------------------------------------------------
// Fused edge pass, lane-owns-edge GEMM + LDS transpose + feature-parallel scatter.
//   emb = relu(ea@W1+b1)@W2+b2 ; msg = relu(h[src]+emb) ; agg[dst] += msg
// Block = 128 threads (2 waves); each wave owns a 64-edge tile.
// Weights are read as wave-uniform scalars (s_load) -> 1 VALU instr per MAC.
__global__ __launch_bounds__(128, 2) void edge_fused(
    const float* __restrict__ hin,       // [NN,64]
    const float* __restrict__ eattr,     // [NE,32]
    const int*   __restrict__ eidx,      // [2,NE]
    const float* __restrict__ w1,        // [32,64] (layer slice)
    const float* __restrict__ b1,        // [64]
    const float* __restrict__ w2,        // [64,64]
    const float* __restrict__ b2,        // [64]
    float*       __restrict__ agg)       // [NN,64]
{
    __shared__ float lds[2][64 * 66];    // per-wave scratch (t: stride 66; emb: stride 64)
    const int lane = threadIdx.x & 63;
    const int wv   = threadIdx.x >> 6;
    float* R = &lds[wv][0];

    const long base = ((long)blockIdx.x * 2 + wv) * 64;
    const int  e    = (int)min(base + lane, (long)(NE - 1));  // clamp ghost lanes

    // ---- GEMM1: t[j] = relu( sum_i a_i * w1[i][j] + b1[j] ) ----
    float t[HH];
    #pragma unroll
    for (int j = 0; j < HH; ++j) t[j] = b1[j];
    const float* ap = eattr + (size_t)e * EF;
    for (int c = 0; c < 8; ++c) {               // dynamic loop: keeps code small
        const float4 av = *(const float4*)(ap + c * 4);
        const float* wr = w1 + c * 4 * HH;
        #pragma unroll
        for (int q = 0; q < 4; ++q) {
            const float aq = (&av.x)[q];
            #pragma unroll
            for (int j = 0; j < HH; ++j)
                t[j] = fmaf(aq, wr[q * HH + j], t[j]);
        }
    }
    // relu, stash per-lane row to LDS (stride 66: 2-way bank alias = free)
    #pragma unroll
    for (int j = 0; j < HH; ++j) R[lane * 66 + j] = fmaxf(t[j], 0.0f);

    // ---- GEMM2: emb[k] = sum_j t_j * w2[j][k] + b2[k] ----
    float emb[HH];
    #pragma unroll
    for (int k = 0; k < HH; ++k) emb[k] = b2[k];
    for (int j = 0; j < HH; ++j) {              // dynamic loop
        const float tj = R[lane * 66 + j];
        const float* wr = w2 + j * HH;
        #pragma unroll
        for (int k = 0; k < HH; ++k) emb[k] = fmaf(tj, wr[k], emb[k]);
    }

    // ---- transpose stash: emb of edge(lane), feat k -> R[lane*64 + ((k+lane)&63)]
    #pragma unroll
    for (int k = 0; k < HH; ++k) R[lane * 64 + ((k + lane) & 63)] = emb[k];
    __syncthreads();

    // ---- phase 2: feature-parallel message + scatter (lane = feature) ----
    const int lim = (int)min((long)64, (long)NE - base);
    for (int e2 = 0; e2 < lim; ++e2) {
        const int ge  = (int)base + e2;
        const int src = eidx[ge];               // uniform -> s_load
        const int dst = eidx[NE + ge];
        const float emv = R[e2 * 64 + ((lane + e2) & 63)];
        const float msg = fmaxf(hin[(size_t)src * HH + lane] + emv, 0.0f);
        atomicAdd(&agg[(size_t)dst * HH + lane], msg);
    }
}

// ---------------------------------------------------------------------------
// Node pass: z=(1+eps)*h+agg ; v=relu(relu(z@W1+b1)@W2+b2) ; v written in-place
// into agg; per-feature sum/sumsq accumulated for BN.
__global__ __launch_bounds__(256, 2) void node_kernel(
    const float* __restrict__ hin,
    float*       agg,                    // in: agg, out: v (aliased on purpose)
    const float* __restrict__ w1, const float* __restrict__ b1,
    const float* __restrict__ w2, const float* __restrict__ b2,
    const float* __restrict__ epsp,
    float*       __restrict__ stats)     // [0:64] sum, [64:128] sumsq
{
    const int lane   = threadIdx.x & 63;
    const int wave   = (blockIdx.x * blockDim.x + threadIdx.x) >> 6;
    const int nwaves = (gridDim.x * blockDim.x) >> 6;

    float w1c[HH], w2c[HH];
    #pragma unroll
    for (int i = 0; i < HH; ++i) w1c[i] = w1[i * HH + lane];
    #pragma unroll
    for (int i = 0; i < HH; ++i) w2c[i] = w2[i * HH + lane];
    const float b1j = b1[lane];
    const float b2j = b2[lane];
    const float epsv = 1.0f + epsp[0];

    float s1 = 0.0f, s2 = 0.0f;
    for (int n = wave; n < NN; n += nwaves) {
        const float z = fmaf(epsv, hin[n * HH + lane], agg[n * HH + lane]);
        float u = b1j;
        #pragma unroll
        for (int k = 0; k < HH; ++k) u = fmaf(bcastf(z, k), w1c[k], u);
        u = fmaxf(u, 0.0f);
        float v = b2j;
        #pragma unroll
        for (int k = 0; k < HH; ++k) v = fmaf(bcastf(u, k), w2c[k], v);
        v = fmaxf(v, 0.0f);
        agg[n * HH + lane] = v;
        s1 += v;
        s2 += v * v;
    }
    atomicAdd(&stats[lane], s1);
    atomicAdd(&stats[64 + lane], s2);
}

// ---------------------------------------------------------------------------
__global__ void bn_finalize(float* stats) {
    int j = threadIdx.x;
    if (j < HH) {
        float mu  = stats[j] * (1.0f / NN);
        float var = stats[64 + j] * (1.0f / NN) - mu * mu;
        stats[128 + j] = mu;
        stats[192 + j] = 1.0f / sqrtf(var + 1e-5f);
    }
}

// BN apply + segmented graph-pool accumulation (batch is sorted!).
// One wave per CHUNK consecutive nodes; lane = feature; flush on graph change.
#define CHUNK 256
__global__ void bn_apply(
    const float* __restrict__ v, const float* __restrict__ stats,
    const float* __restrict__ gamma, const float* __restrict__ beta,
    const int* __restrict__ batch,
    float* __restrict__ hout, float* __restrict__ pooled, int layer)
{
    const int lane = threadIdx.x & 63;
    const int wv   = (blockIdx.x * blockDim.x + threadIdx.x) >> 6;
    const int n0   = wv * CHUNK;
    if (n0 >= NN) return;
    const int n1 = min(n0 + CHUNK, NN);
    const float mu = stats[128 + lane], rs = stats[192 + lane];
    const float ga = gamma[lane],       be = beta[lane];
    float acc = 0.0f;
    int cur = batch[n0];
    for (int n = n0; n < n1; ++n) {
        const int b = batch[n];                       // uniform
        const float z = (v[(size_t)n * HH + lane] - mu) * rs * ga + be;
        hout[(size_t)n * HH + lane] = z;
        if (b != cur) {                               // uniform branch
            atomicAdd(&pooled[(size_t)cur * (NL * HH) + layer * HH + lane], acc);
            acc = 0.0f; cur = b;
        }
        acc += z;
    }
    atomicAdd(&pooled[(size_t)cur * (NL * HH) + layer * HH + lane], acc);
}

// ---------------------------------------------------------------------------
// Graph head: g = relu(mean_pool @ fc0 + b)*w ; s_acc[sgb[g]] += g
__global__ __launch_bounds__(256, 1) void graph_kernel(
    const float* __restrict__ pooled, const float* __restrict__ cnt,
    const float* __restrict__ fc0_w, const float* __restrict__ fc0_b,
    const float* __restrict__ wts, const int* __restrict__ sgb,
    float* __restrict__ s_acc)
{
    __shared__ float w[NL * HH * HH];   // 192x64 = 48KB
    for (int i = threadIdx.x; i < NL * HH * HH; i += blockDim.x) w[i] = fc0_w[i];
    __syncthreads();
    const int lane = threadIdx.x & 63;
    const int g = blockIdx.x * 4 + (threadIdx.x >> 6);
    if (g >= NG) return;
    const float inv = 1.0f / fmaxf(cnt[g], 1.0f);
    float acc = fc0_b[lane];
    #pragma unroll
    for (int c = 0; c < NL; ++c) {
        const float a = pooled[g * (NL * HH) + c * HH + lane] * inv;
        #pragma unroll
        for (int k = 0; k < HH; ++k)
            acc = fmaf(bcastf(a, k), w[(c * HH + k) * HH + lane], acc);
    }
    const float og = fmaxf(acc, 0.0f) * wts[g];
    atomicAdd(&s_acc[sgb[g] * HH + lane], og);
}

// Final head: s -> fc1 relu -> fc2 relu -> pred
__global__ __launch_bounds__(256, 1) void final_kernel(
    const float* __restrict__ s_acc, const float* __restrict__ norm,
    const float* __restrict__ fc1_w, const float* __restrict__ fc1_b,
    const float* __restrict__ fc2_w, const float* __restrict__ fc2_b,
    const float* __restrict__ pw, const float* __restrict__ pb,
    float* __restrict__ out)
{
    const int lane = threadIdx.x & 63;
    const int s = blockIdx.x * 4 + (threadIdx.x >> 6);
    if (s >= NSG) return;
    const float xv = s_acc[s * HH + lane] / fmaxf(norm[s], 1e-12f);
    float u = fc1_b[lane];
    #pragma unroll
    for (int k = 0; k < HH; ++k) u = fmaf(bcastf(xv, k), fc1_w[k * HH + lane], u);
    u = fmaxf(u, 0.0f);
    float v = fc2_b[lane];
    #pragma unroll
    for (int k = 0; k < HH; ++k) v = fmaf(bcastf(u, k), fc2_w[k * HH + lane], v);
    v = fmaxf(v, 0.0f);
    float o = pb[lane & 31];
    #pragma unroll
    for (int k = 0; k < HH; ++k) o = fmaf(bcastf(v, k), pw[k * NOUT + (lane & 31)], o);
    if (lane < NOUT) out[s * NOUT + lane] = o;
}

// ---------------------------------------------------------------------------
extern "C" void kernel_launch(void* const* d_in, const int* in_sizes, int n_in,
                              void* d_out, int out_size, void* d_ws, size_t ws_size,
                              hipStream_t stream)
{
    const float* x        = (const float*)d_in[0];
    const int*   eidx     = (const int*)d_in[1];
    const float* eattr    = (const float*)d_in[2];
    const int*   batch    = (const int*)d_in[3];
    const float* weights  = (const float*)d_in[4];
    const int*   sgb      = (const int*)d_in[5];
    const float* be_w1    = (const float*)d_in[6];
    const float* be_b1    = (const float*)d_in[7];
    const float* be_w2    = (const float*)d_in[8];
    const float* be_b2    = (const float*)d_in[9];
    const float* mlp_w1   = (const float*)d_in[10];
    const float* mlp_b1   = (const float*)d_in[11];
    const float* mlp_w2   = (const float*)d_in[12];
    const float* mlp_b2   = (const float*)d_in[13];
    const float* eps      = (const float*)d_in[14];
    const float* bn_gamma = (const float*)d_in[15];
    const float* bn_beta  = (const float*)d_in[16];
    const float* fc0_w    = (const float*)d_in[17];
    const float* fc0_b    = (const float*)d_in[18];
    const float* fc1_w    = (const float*)d_in[19];
    const float* fc1_b    = (const float*)d_in[20];
    const float* fc2_w    = (const float*)d_in[21];
    const float* fc2_b    = (const float*)d_in[22];
    const float* pred_w   = (const float*)d_in[23];
    const float* pred_b   = (const float*)d_in[24];
    float* out = (float*)d_out;

    float* ws     = (float*)d_ws;
    float* h_buf  = ws;                               // NN*64
    float* agg    = ws + (size_t)NN * HH;             // NN*64 (also holds v)
    float* pooled = ws + (size_t)NN * HH * 2;         // NG*192
    float* cnt    = pooled + (size_t)NG * NL * HH;    // NG
    float* stats  = cnt + NG;                         // 256
    float* s_acc  = stats + 256;                      // NSG*64
    float* norm   = s_acc + (size_t)NSG * HH;         // NSG

    // zero all accumulators used across the whole pass (contiguous block)
    size_t acc_floats = (size_t)NG * NL * HH + NG + 256 + (size_t)NSG * HH + NSG;
    hipMemsetAsync(pooled, 0, acc_floats * sizeof(float), stream);

    cnt_kernel<<<(NN + 255) / 256, 256, 0, stream>>>(batch, cnt);
    norm_kernel<<<4, 256, 0, stream>>>(sgb, weights, norm);

    const float* hin = x;
    const int edge_blocks = (NE + 127) / 128;   // 2 tiles (waves) per block
    const int bn_waves    = (NN + CHUNK - 1) / CHUNK;
    const int bn_blocks   = (bn_waves + 3) / 4;
    for (int l = 0; l < NL; ++l) {
        hipMemsetAsync(agg, 0, (size_t)NN * HH * sizeof(float), stream);
        hipMemsetAsync(stats, 0, 256 * sizeof(float), stream);
        edge_fused<<<edge_blocks, 128, 0, stream>>>(
            hin, eattr, eidx,
            be_w1 + l * EF * HH, be_b1 + l * HH,
            be_w2 + l * HH * HH, be_b2 + l * HH, agg);
        node_kernel<<<1024, 256, 0, stream>>>(
            hin, agg,
            mlp_w1 + l * HH * HH, mlp_b1 + l * HH,
            mlp_w2 + l * HH * HH, mlp_b2 + l * HH,
            eps + l, stats);
        bn_finalize<<<1, 64, 0, stream>>>(stats);
        bn_apply<<<bn_blocks, 256, 0, stream>>>(
            agg, stats, bn_gamma + l * HH, bn_beta + l * HH,
            batch, h_buf, pooled, l);
        hin = h_buf;
    }

    graph_kernel<<<NG / 4, 256, 0, stream>>>(pooled, cnt, fc0_w, fc0_b,
                                             weights, sgb, s_acc);
    final_kernel<<<NSG / 4, 256, 0, stream>>>(s_acc, norm, fc1_w, fc1_b,
                                              fc2_w, fc2_b, pred_w, pred_b, out);
}

// Round 3
// 1939.036 us; speedup vs baseline: 1.2568x; 1.2568x over previous
//
#include <hip/hip_runtime.h>

#define NN 100000      // nodes
#define NE 1000000     // edges
#define NG 1024        // graphs
#define NSG 128        // subgraphs
#define EF 32          // edge feature dim
#define HH 64          // hidden
#define NOUT 32        // output classes
#define NL 3           // layers

// wave-uniform broadcast of lane l's value (v_readlane -> SGPR)
__device__ __forceinline__ float bcastf(float v, int l) {
    return __int_as_float(__builtin_amdgcn_readlane(__float_as_int(v), l));
}

// wave-internal LDS producer->consumer handoff (no cross-wave sharing)
__device__ __forceinline__ void wave_lds_sync() {
    __builtin_amdgcn_wave_barrier();
    asm volatile("s_waitcnt lgkmcnt(0)" ::: "memory");
    __builtin_amdgcn_wave_barrier();
}

// ---------------------------------------------------------------------------
__global__ void cnt_kernel(const int* __restrict__ batch, float* __restrict__ cnt) {
    int i = blockIdx.x * blockDim.x + threadIdx.x;
    if (i < NN) atomicAdd(&cnt[batch[i]], 1.0f);
}

__global__ void norm_kernel(const int* __restrict__ sgb, const float* __restrict__ w,
                            float* __restrict__ norm) {
    int i = blockIdx.x * blockDim.x + threadIdx.x;
    if (i < NG) atomicAdd(&norm[sgb[i]], w[i]);
}

// ---------------------------------------------------------------------------
// Edge pass, lane-owns-edge: emb = relu(ea@W1+b1)@W2+b2 computed fully in
// registers (weights arrive as wave-uniform s_loads -> 1 VALU instr per MAC),
// then a 32-edge LDS chunk transpose feeds the feature-parallel
// gather(h[src]) + relu + scatter-atomic(agg[dst]) phase.
__global__ __launch_bounds__(256, 4) void edge_fused(
    const float* __restrict__ hin,       // [NN,64]
    const float* __restrict__ eattr,     // [NE,32]
    const int*   __restrict__ eidx,      // [2,NE]
    const float* __restrict__ w1,        // [32,64]
    const float* __restrict__ b1,        // [64]
    const float* __restrict__ w2,        // [64,64]
    const float* __restrict__ b2,        // [64]
    float*       __restrict__ agg)       // [NN,64]
{
    __shared__ float lds[4][32 * 65];
    const int lane = threadIdx.x & 63;
    const int wv   = threadIdx.x >> 6;
    float* R = lds[wv];

    const int tile = blockIdx.x * 4 + wv;        // 15625 tiles of 64 edges
    const int base = tile * 64;
    if (base >= NE) return;
    const int e = base + lane;                   // NE % 64 == 0, no tail

    // per-lane edge attributes
    float a[EF];
    const float4* ap = (const float4*)(eattr + (size_t)e * EF);
    #pragma unroll
    for (int c = 0; c < 8; ++c) {
        const float4 v4 = ap[c];
        a[4*c] = v4.x; a[4*c+1] = v4.y; a[4*c+2] = v4.z; a[4*c+3] = v4.w;
    }

    float emb[HH];
    #pragma unroll
    for (int k = 0; k < HH; ++k) emb[k] = b2[k];

    // j-blocked MLP: t[8] static registers inside a dynamic 8-iter loop
    for (int jb = 0; jb < 8; ++jb) {
        const int j0 = jb * 8;
        float t[8];
        #pragma unroll
        for (int q = 0; q < 8; ++q) t[q] = b1[j0 + q];
        #pragma unroll
        for (int i = 0; i < EF; ++i) {
            const float ai = a[i];
            #pragma unroll
            for (int q = 0; q < 8; ++q)
                t[q] = fmaf(ai, w1[i * HH + j0 + q], t[q]);
        }
        #pragma unroll
        for (int q = 0; q < 8; ++q) {
            const float tq = fmaxf(t[q], 0.0f);
            const float* wr = w2 + (j0 + q) * HH;
            #pragma unroll
            for (int k = 0; k < HH; ++k)
                emb[k] = fmaf(tq, wr[k], emb[k]);
        }
    }

    // phase 2: 32-edge chunks through LDS, feature-parallel scatter
    #pragma unroll
    for (int cb = 0; cb < 2; ++cb) {
        const int r = lane & 31;
        if ((lane >> 5) == cb) {
            #pragma unroll
            for (int k = 0; k < HH; ++k) R[r * 65 + k] = emb[k];
        }
        wave_lds_sync();
        #pragma unroll 4
        for (int e2 = 0; e2 < 32; ++e2) {
            const int ge  = base + cb * 32 + e2;
            const int src = eidx[ge];            // wave-uniform -> s_load
            const int dst = eidx[NE + ge];
            const float emv = R[e2 * 65 + lane];
            const float msg = fmaxf(hin[(size_t)src * HH + lane] + emv, 0.0f);
            atomicAdd(&agg[(size_t)dst * HH + lane], msg);
        }
        wave_lds_sync();
    }
}

// ---------------------------------------------------------------------------
// Node pass, lane-owns-node: z=(1+eps)h+agg ; v=relu(relu(z@W1+b1)@W2+b2);
// LDS chunk transpose -> coalesced in-place store into agg + BN sum/sumsq.
__global__ __launch_bounds__(256, 3) void node_fused(
    const float* __restrict__ hin,
    float*       agg,                    // in: agg, out: v (same rows only)
    const float* __restrict__ w1, const float* __restrict__ b1,
    const float* __restrict__ w2, const float* __restrict__ b2,
    const float* __restrict__ epsp,
    float*       __restrict__ stats)     // [0:64] sum, [64:128] sumsq
{
    __shared__ float lds[4][32 * 65];
    const int lane = threadIdx.x & 63;
    const int wv   = threadIdx.x >> 6;
    float* R = lds[wv];

    const int tile = blockIdx.x * 4 + wv;        // 1563 tiles of <=64 nodes
    const int base = tile * 64;
    if (base >= NN) return;
    const int n = min(base + lane, NN - 1);      // clamp ghost lanes (same tile)
    const float epsv = 1.0f + epsp[0];

    float z[HH];
    const float4* hp = (const float4*)(hin + (size_t)n * HH);
    const float4* gp = (const float4*)(agg + (size_t)n * HH);
    #pragma unroll
    for (int c = 0; c < 16; ++c) {
        const float4 h4 = hp[c];
        const float4 g4 = gp[c];
        z[4*c]   = fmaf(epsv, h4.x, g4.x);
        z[4*c+1] = fmaf(epsv, h4.y, g4.y);
        z[4*c+2] = fmaf(epsv, h4.z, g4.z);
        z[4*c+3] = fmaf(epsv, h4.w, g4.w);
    }

    float v[HH];
    #pragma unroll
    for (int k = 0; k < HH; ++k) v[k] = b2[k];

    for (int jb = 0; jb < 8; ++jb) {
        const int j0 = jb * 8;
        float t[8];
        #pragma unroll
        for (int q = 0; q < 8; ++q) t[q] = b1[j0 + q];
        #pragma unroll
        for (int i = 0; i < HH; ++i) {
            const float zi = z[i];
            #pragma unroll
            for (int q = 0; q < 8; ++q)
                t[q] = fmaf(zi, w1[i * HH + j0 + q], t[q]);
        }
        #pragma unroll
        for (int q = 0; q < 8; ++q) {
            const float tq = fmaxf(t[q], 0.0f);
            const float* wr = w2 + (j0 + q) * HH;
            #pragma unroll
            for (int k = 0; k < HH; ++k)
                v[k] = fmaf(tq, wr[k], v[k]);
        }
    }
    #pragma unroll
    for (int k = 0; k < HH; ++k) v[k] = fmaxf(v[k], 0.0f);

    const int valid = min(64, NN - base);
    float s1 = 0.0f, s2 = 0.0f;
    #pragma unroll
    for (int cb = 0; cb < 2; ++cb) {
        const int r = lane & 31;
        if ((lane >> 5) == cb && cb * 32 + r < valid) {
            #pragma unroll
            for (int k = 0; k < HH; ++k) R[r * 65 + k] = v[k];
        }
        wave_lds_sync();
        const int lim = min(max(valid - cb * 32, 0), 32);
        for (int e2 = 0; e2 < lim; ++e2) {
            const int nn2 = base + cb * 32 + e2;
            const float val = R[e2 * 65 + lane];
            agg[(size_t)nn2 * HH + lane] = val;
            s1 += val;
            s2 += val * val;
        }
        wave_lds_sync();
    }
    atomicAdd(&stats[lane], s1);
    atomicAdd(&stats[64 + lane], s2);
}

// ---------------------------------------------------------------------------
__global__ void bn_finalize(float* stats) {
    int j = threadIdx.x;
    if (j < HH) {
        float mu  = stats[j] * (1.0f / NN);
        float var = stats[64 + j] * (1.0f / NN) - mu * mu;
        stats[128 + j] = mu;
        stats[192 + j] = 1.0f / sqrtf(var + 1e-5f);
    }
}

// BN apply + segmented graph-pool accumulation (batch sorted).
#define CHUNK 64
__global__ void bn_apply(
    const float* __restrict__ v, const float* __restrict__ stats,
    const float* __restrict__ gamma, const float* __restrict__ beta,
    const int* __restrict__ batch,
    float* __restrict__ hout, float* __restrict__ pooled, int layer)
{
    const int lane = threadIdx.x & 63;
    const int wv   = (blockIdx.x * blockDim.x + threadIdx.x) >> 6;
    const int n0   = wv * CHUNK;
    if (n0 >= NN) return;
    const int n1 = min(n0 + CHUNK, NN);
    const float mu = stats[128 + lane], rs = stats[192 + lane];
    const float ga = gamma[lane],       be = beta[lane];
    float acc = 0.0f;
    int cur = batch[n0];
    for (int n = n0; n < n1; ++n) {
        const int b = batch[n];                       // uniform
        const float z = (v[(size_t)n * HH + lane] - mu) * rs * ga + be;
        hout[(size_t)n * HH + lane] = z;
        if (b != cur) {                               // uniform branch
            atomicAdd(&pooled[(size_t)cur * (NL * HH) + layer * HH + lane], acc);
            acc = 0.0f; cur = b;
        }
        acc += z;
    }
    atomicAdd(&pooled[(size_t)cur * (NL * HH) + layer * HH + lane], acc);
}

// ---------------------------------------------------------------------------
__global__ __launch_bounds__(256, 1) void graph_kernel(
    const float* __restrict__ pooled, const float* __restrict__ cnt,
    const float* __restrict__ fc0_w, const float* __restrict__ fc0_b,
    const float* __restrict__ wts, const int* __restrict__ sgb,
    float* __restrict__ s_acc)
{
    __shared__ float w[NL * HH * HH];   // 48KB
    for (int i = threadIdx.x; i < NL * HH * HH; i += blockDim.x) w[i] = fc0_w[i];
    __syncthreads();
    const int lane = threadIdx.x & 63;
    const int g = blockIdx.x * 4 + (threadIdx.x >> 6);
    if (g >= NG) return;
    const float inv = 1.0f / fmaxf(cnt[g], 1.0f);
    float acc = fc0_b[lane];
    #pragma unroll
    for (int c = 0; c < NL; ++c) {
        const float a = pooled[g * (NL * HH) + c * HH + lane] * inv;
        #pragma unroll
        for (int k = 0; k < HH; ++k)
            acc = fmaf(bcastf(a, k), w[(c * HH + k) * HH + lane], acc);
    }
    const float og = fmaxf(acc, 0.0f) * wts[g];
    atomicAdd(&s_acc[sgb[g] * HH + lane], og);
}

__global__ __launch_bounds__(256, 1) void final_kernel(
    const float* __restrict__ s_acc, const float* __restrict__ norm,
    const float* __restrict__ fc1_w, const float* __restrict__ fc1_b,
    const float* __restrict__ fc2_w, const float* __restrict__ fc2_b,
    const float* __restrict__ pw, const float* __restrict__ pb,
    float* __restrict__ out)
{
    const int lane = threadIdx.x & 63;
    const int s = blockIdx.x * 4 + (threadIdx.x >> 6);
    if (s >= NSG) return;
    const float xv = s_acc[s * HH + lane] / fmaxf(norm[s], 1e-12f);
    float u = fc1_b[lane];
    #pragma unroll
    for (int k = 0; k < HH; ++k) u = fmaf(bcastf(xv, k), fc1_w[k * HH + lane], u);
    u = fmaxf(u, 0.0f);
    float v = fc2_b[lane];
    #pragma unroll
    for (int k = 0; k < HH; ++k) v = fmaf(bcastf(u, k), fc2_w[k * HH + lane], v);
    v = fmaxf(v, 0.0f);
    float o = pb[lane & 31];
    #pragma unroll
    for (int k = 0; k < HH; ++k) o = fmaf(bcastf(v, k), pw[k * NOUT + (lane & 31)], o);
    if (lane < NOUT) out[s * NOUT + lane] = o;
}

// ---------------------------------------------------------------------------
extern "C" void kernel_launch(void* const* d_in, const int* in_sizes, int n_in,
                              void* d_out, int out_size, void* d_ws, size_t ws_size,
                              hipStream_t stream)
{
    const float* x        = (const float*)d_in[0];
    const int*   eidx     = (const int*)d_in[1];
    const float* eattr    = (const float*)d_in[2];
    const int*   batch    = (const int*)d_in[3];
    const float* weights  = (const float*)d_in[4];
    const int*   sgb      = (const int*)d_in[5];
    const float* be_w1    = (const float*)d_in[6];
    const float* be_b1    = (const float*)d_in[7];
    const float* be_w2    = (const float*)d_in[8];
    const float* be_b2    = (const float*)d_in[9];
    const float* mlp_w1   = (const float*)d_in[10];
    const float* mlp_b1   = (const float*)d_in[11];
    const float* mlp_w2   = (const float*)d_in[12];
    const float* mlp_b2   = (const float*)d_in[13];
    const float* eps      = (const float*)d_in[14];
    const float* bn_gamma = (const float*)d_in[15];
    const float* bn_beta  = (const float*)d_in[16];
    const float* fc0_w    = (const float*)d_in[17];
    const float* fc0_b    = (const float*)d_in[18];
    const float* fc1_w    = (const float*)d_in[19];
    const float* fc1_b    = (const float*)d_in[20];
    const float* fc2_w    = (const float*)d_in[21];
    const float* fc2_b    = (const float*)d_in[22];
    const float* pred_w   = (const float*)d_in[23];
    const float* pred_b   = (const float*)d_in[24];
    float* out = (float*)d_out;

    float* ws     = (float*)d_ws;
    float* h_buf  = ws;                               // NN*64
    float* agg    = ws + (size_t)NN * HH;             // NN*64 (also holds v)
    float* pooled = ws + (size_t)NN * HH * 2;         // NG*192
    float* cnt    = pooled + (size_t)NG * NL * HH;    // NG
    float* stats  = cnt + NG;                         // 256
    float* s_acc  = stats + 256;                      // NSG*64
    float* norm   = s_acc + (size_t)NSG * HH;         // NSG

    size_t acc_floats = (size_t)NG * NL * HH + NG + 256 + (size_t)NSG * HH + NSG;
    hipMemsetAsync(pooled, 0, acc_floats * sizeof(float), stream);

    cnt_kernel<<<(NN + 255) / 256, 256, 0, stream>>>(batch, cnt);
    norm_kernel<<<4, 256, 0, stream>>>(sgb, weights, norm);

    const float* hin = x;
    const int edge_tiles = NE / 64;                   // 15625
    const int edge_blocks = (edge_tiles + 3) / 4;     // 4 waves/block
    const int node_tiles = (NN + 63) / 64;            // 1563
    const int node_blocks = (node_tiles + 3) / 4;
    const int bn_waves  = (NN + CHUNK - 1) / CHUNK;
    const int bn_blocks = (bn_waves + 3) / 4;
    for (int l = 0; l < NL; ++l) {
        hipMemsetAsync(agg, 0, (size_t)NN * HH * sizeof(float), stream);
        hipMemsetAsync(stats, 0, 256 * sizeof(float), stream);
        edge_fused<<<edge_blocks, 256, 0, stream>>>(
            hin, eattr, eidx,
            be_w1 + l * EF * HH, be_b1 + l * HH,
            be_w2 + l * HH * HH, be_b2 + l * HH, agg);
        node_fused<<<node_blocks, 256, 0, stream>>>(
            hin, agg,
            mlp_w1 + l * HH * HH, mlp_b1 + l * HH,
            mlp_w2 + l * HH * HH, mlp_b2 + l * HH,
            eps + l, stats);
        bn_finalize<<<1, 64, 0, stream>>>(stats);
        bn_apply<<<bn_blocks, 256, 0, stream>>>(
            agg, stats, bn_gamma + l * HH, bn_beta + l * HH,
            batch, h_buf, pooled, l);
        hin = h_buf;
    }

    graph_kernel<<<NG / 4, 256, 0, stream>>>(pooled, cnt, fc0_w, fc0_b,
                                             weights, sgb, s_acc);
    final_kernel<<<NSG / 4, 256, 0, stream>>>(s_acc, norm, fc1_w, fc1_b,
                                              fc2_w, fc2_b, pred_w, pred_b, out);
}